// Round 11
// baseline (299.452 us; speedup 1.0000x reference)
//
#include <hip/hip_runtime.h>

#define HID 50
#define IND 8
#define TLEN 512
#define NB 16         // batch columns per block — all 16 MFMA N cols real
#define CH 128        // x chunk timesteps staged in LDS (4 chunks/sequence)
#define XSTR 1032     // x_lds per-column stride in halves
#define BSTR 72       // B row stride in halves (16B-aligned rows)
#define NWAVE 7       // wave w owns tiles 2w, 2w+1 (wave 6: tile 12 only)

typedef _Float16 f16x8 __attribute__((ext_vector_type(8)));
typedef _Float16 f16x4 __attribute__((ext_vector_type(4)));
typedef float f32x4 __attribute__((ext_vector_type(4)));

__device__ __forceinline__ float fast_sigmoid(float v) {
    float e = __builtin_amdgcn_exp2f(-1.44269504f * v);
    return __builtin_amdgcn_rcpf(1.0f + e);
}
__device__ __forceinline__ float fast_tanh(float v) {
    float e = __builtin_amdgcn_exp2f(2.88539008f * v);
    return 1.0f - 2.0f * __builtin_amdgcn_rcpf(e + 1.0f);
}

// Round-11: the per-step LDS broadcast burst is 2 b128 reads PER WAVE
// (B is identical for all waves — reads are pure duplication; r9/r10
// SQ_LDS_BANK_CONFLICT arithmetic pinned ~310 cyc/step of serialized LDS
// port time). Pair tiles 2-per-wave: 7 waves -> 14 reads/step, shared
// bf0/bf1 across the wave's two MFMA pairs. Everything else = round 10:
// gate-aligned M packing (R=4*jh+g), in-register gates + fp32 h,
// double-buffered B with ONE barrier/step, quad-3 reads x_t from x_lds.
__global__ __launch_bounds__(NWAVE * 64, 1) void gru_mfma7(
    const float* __restrict__ x,      // [B, T, 8]
    const float* __restrict__ W_ih,   // [150, 8]
    const float* __restrict__ W_hh,   // [150, 50]
    const float* __restrict__ b_ih,   // [150]
    const float* __restrict__ b_hh,   // [150]
    const float* __restrict__ W_out,  // [1, 50]
    const float* __restrict__ b_out,  // [1]
    float* __restrict__ out)          // [B]
{
    const int tid  = threadIdx.x;     // 448 threads = 7 waves
    const int wave = tid >> 6;
    const int lane = tid & 63;
    const int m16  = lane & 15;
    const int quad = lane >> 4;
    const int bb   = blockIdx.x;

    const int T0 = 2 * wave;                      // always valid (0..12)
    const int T1 = 2 * wave + 1;                  // wave 6: 13 -> invalid
    const bool has1 = (T1 <= 12);
    const int jh0 = 4 * T0 + quad;                // 0..51
    const int jh1 = 4 * T1 + quad;                // up to 55 (guarded)

    __shared__ _Float16 x_lds[NB * XSTR];         // 33 KB
    __shared__ _Float16 B_lds[2][16 * BSTR];      // 4.6 KB
    __shared__ float    red[NB * 56];             // 3.5 KB

    // ---- one-time: A fragments + biases into VGPRs ----
    // A[m=lane&15][k=quad*8+j] (HW-verified). x block at k=56..63.
    auto aval = [&](int T, int k) -> float {
        const int R  = 16 * T + m16;
        const int rj = R >> 2;
        const int g  = R & 3;
        if (rj >= HID) return 0.f;
        if (g <= 1) {
            if (k < HID) return W_hh[(g * HID + rj) * HID + k];
            if (k >= 56) return W_ih[(g * HID + rj) * IND + (k - 56)];
            return 0.f;
        }
        if (g == 2) return (k < HID) ? W_hh[(2 * HID + rj) * HID + k] : 0.f;
        return (k >= 56) ? W_ih[(2 * HID + rj) * IND + (k - 56)] : 0.f;
    };
    auto bval = [&](int jh, int r) -> float {
        if (jh >= HID) return 0.f;
        if (r == 0) return b_ih[jh] + b_hh[jh];
        if (r == 1) return b_ih[HID + jh] + b_hh[HID + jh];
        if (r == 2) return b_hh[2 * HID + jh];
        return b_ih[2 * HID + jh];
    };

    f16x8 a0[2], a1[2];
    f32x4 bias[2];
#pragma unroll
    for (int j = 0; j < 8; ++j) {
        a0[0][j] = (_Float16)aval(T0, quad * 8 + j);
        a1[0][j] = (_Float16)aval(T0, 32 + quad * 8 + j);
        a0[1][j] = has1 ? (_Float16)aval(T1, quad * 8 + j)      : (_Float16)0.f;
        a1[1][j] = has1 ? (_Float16)aval(T1, 32 + quad * 8 + j) : (_Float16)0.f;
    }
#pragma unroll
    for (int r = 0; r < 4; ++r) {
        bias[0][r] = bval(jh0, r);
        bias[1][r] = has1 ? bval(jh1, r) : 0.f;
    }
    const f32x4 zero4 = {0.f, 0.f, 0.f, 0.f};
    float h0 = 0.f, h1 = 0.f;

    // ---- x chunk staging: 128 timesteps, per-column contiguous ----
    // 4096 float4 per chunk, strided over 448 threads (coalesced global).
    auto stage_chunk = [&](int c) {
        const float* xbase = x + (size_t)(bb * NB) * TLEN * IND + (size_t)c * CH * IND;
        for (int f = tid; f < NB * (CH * IND / 4); f += NWAVE * 64) {
            const int n    = f >> 8;              // 256 float4 per column
            const int fidx = f & 255;
            const float4 v = ((const float4*)(xbase + (size_t)n * TLEN * IND))[fidx];
            const int trel = fidx >> 1;
            const int d    = (fidx & 1) * 4;
            *(f16x4*)&x_lds[n * XSTR + trel * 8 + d] =
                f16x4{(_Float16)v.x, (_Float16)v.y, (_Float16)v.z, (_Float16)v.w};
        }
    };

    // ---- init: zero both B buffers; stage chunk 0 ----
    for (int idx = tid; idx < 2 * 16 * BSTR; idx += NWAVE * 64)
        B_lds[0][idx] = (_Float16)0.f;            // flat across both buffers
    stage_chunk(0);
    __syncthreads();

    // ---- the recurrence: 2 tiles/wave, shared B reads, 1 barrier/step ----
    auto step = [&](int t, int cur, int nxt) {
        // ONE bf0/bf1 pair per wave, shared by both tiles' MFMAs
        const f16x8 bf0 = *(const f16x8*)&B_lds[cur][m16 * BSTR + quad * 8];
        const _Float16* bf1p = (quad == 3)
            ? &x_lds[m16 * XSTR + (t & (CH - 1)) * 8]
            : &B_lds[cur][m16 * BSTR + 32 + quad * 8];
        const f16x8 bf1 = *(const f16x8*)bf1p;

        // 4 MFMAs, all independent accumulators
        const f32x4 c0 = __builtin_amdgcn_mfma_f32_16x16x32_f16(a0[0], bf0, bias[0], 0, 0, 0);
        const f32x4 d0 = __builtin_amdgcn_mfma_f32_16x16x32_f16(a1[0], bf1, zero4,   0, 0, 0);
        const f32x4 c1 = __builtin_amdgcn_mfma_f32_16x16x32_f16(a0[1], bf0, bias[1], 0, 0, 0);
        const f32x4 d1 = __builtin_amdgcn_mfma_f32_16x16x32_f16(a1[1], bf1, zero4,   0, 0, 0);

        {
            const float r  = fast_sigmoid(c0[0] + d0[0]);
            const float z  = fast_sigmoid(c0[1] + d0[1]);
            const float nn = fast_tanh((c0[3] + d0[3]) + r * (c0[2] + d0[2]));
            h0 = nn + z * (h0 - nn);
            if (jh0 < HID)
                B_lds[nxt][m16 * BSTR + jh0] = (_Float16)h0;
        }
        if (has1) {
            const float r  = fast_sigmoid(c1[0] + d1[0]);
            const float z  = fast_sigmoid(c1[1] + d1[1]);
            const float nn = fast_tanh((c1[3] + d1[3]) + r * (c1[2] + d1[2]));
            h1 = nn + z * (h1 - nn);
            if (jh1 < HID)
                B_lds[nxt][m16 * BSTR + jh1] = (_Float16)h1;
        }
        __syncthreads();   // the only per-step barrier
    };

    for (int t2 = 0; t2 < TLEN; t2 += 2) {
        if ((t2 & (CH - 1)) == 0 && t2 != 0) {     // t2 = 128, 256, 384
            stage_chunk(t2 >> 7);
            __syncthreads();
        }
        step(t2,     0, 1);
        step(t2 + 1, 1, 0);
    }

    // ---- head: out[n] = sum_jh h(jh,n) * W_out[jh] + b_out ----
    if (jh0 < HID) red[m16 * 56 + jh0] = h0 * W_out[jh0];
    if (has1 && jh1 < HID) red[m16 * 56 + jh1] = h1 * W_out[jh1];
    __syncthreads();
    if (tid < NB) {
        float s = b_out[0];
        for (int j = 0; j < HID; ++j) s += red[tid * 56 + j];
        out[bb * NB + tid] = s;
    }
}

extern "C" void kernel_launch(void* const* d_in, const int* in_sizes, int n_in,
                              void* d_out, int out_size, void* d_ws, size_t ws_size,
                              hipStream_t stream) {
    const float* x     = (const float*)d_in[0];
    const float* W_ih  = (const float*)d_in[1];
    const float* W_hh  = (const float*)d_in[2];
    const float* b_ih  = (const float*)d_in[3];
    const float* b_hh  = (const float*)d_in[4];
    const float* W_out = (const float*)d_in[5];
    const float* b_out = (const float*)d_in[6];
    float* out = (float*)d_out;

    const int B = in_sizes[0] / (TLEN * IND);   // 4096
    gru_mfma7<<<B / NB, NWAVE * 64, 0, stream>>>(x, W_ih, W_hh, b_ih, b_hh, W_out, b_out, out);
}